// Round 8
// baseline (77.021 us; speedup 1.0000x reference)
//
#include <hip/hip_runtime.h>

#define SEQ   512
#define BATCH 256
#define NH    6   // helper partial slots (waves 1,2,3,5,6,7)

// Uniform-index lane broadcast via v_readlane (index must be SGPR/imm).
__device__ __forceinline__ float bcast_f(float v, int srcLane) {
    return __int_as_float(__builtin_amdgcn_readlane(__float_as_int(v), srcLane));
}
// gfx950: v_log_f32 is log2, v_exp_f32 is exp2.
__device__ __forceinline__ float flog2(float x) { return __builtin_amdgcn_logf(x); }
__device__ __forceinline__ float fexp2(float x) { return __builtin_amdgcn_exp2f(x); }
// Barrier draining only LDS ops (lgkmcnt); __syncthreads() would also drain vmcnt.
__device__ __forceinline__ void lds_barrier() {
    __asm__ __volatile__("s_waitcnt lgkmcnt(0)\ns_barrier" ::: "memory");
}

// ============================================================================
// Structure: ONE barrier per phase. Wave0 integrates the "panel"
// (cols of block J -> rows of block J+1) into its own diag loop, using em_j
// live in registers; helpers only do deep blocks + x-only table precompute.
// Dependency proof:
//   row block R total = panel (cols R-1, wave0 @ phase R-1, in accN)
//                     + deep  (cols 0..R-2, helpers @ phases 1..R-1)
//                     + diag  (within R, wave0 @ phase R).
//   Deep writes for row R complete by end-barrier of phase R-1; wave0 merges
//   row R at start of phase R. Helpers read expm[J-1] at phase J start
//   (published by wave0 before phase J-1's end barrier). Tables for phase J+1
//   (Tt: block J+1 self-pairs; Pt: rows J+2 x cols J+1) are written during
//   phase J into buffer (J+1)&1 while wave0 reads buffer J&1 -> no overlap.
// ============================================================================

template <int CNT>
__device__ __forceinline__ void run_helper(const int start, const int hidx,
                                           const int lane, const float a,
                                           const float c,
                                           float (&x_lds)[SEQ],
                                           float (&expm_lds)[SEQ],
                                           float (&part_lds)[NH][8][64],
                                           float2 (&Tt)[2][64][64],
                                           float2 (&Pt)[2][64][64]) {
    for (int J = 0; J < 8; ++J) {
        if (J >= 1 && J <= 6) {
            // ---- deep: cols J-1 -> rows J+1..7 (overlaps wave0's diag J).
            const float evec = expm_lds[((J - 1) << 6) | lane];
            const float xv   = x_lds[((J - 1) << 6) | lane];
            const float pvec = -fmaf(c, evec, a);   // p for all 64 cols, 1 op
            float pj[CNT], xj[CNT];
#pragma unroll
            for (int k = 0; k < CNT; ++k) {
                pj[k] = bcast_f(pvec, start + k);
                xj[k] = bcast_f(xv,   start + k);
            }
            float xr = x_lds[((J + 1) << 6) | lane];
            for (int R = J + 1; R < 8; ++R) {
                const int Rn = (R < 7) ? R + 1 : R;              // prefetch
                const float xr_next = x_lds[(Rn << 6) | lane];
                float acc0 = 0.0f, acc1 = 0.0f;
#pragma unroll
                for (int k = 0; k < CNT; ++k) {
                    const float L = flog2(fmaxf(xr - xj[k], 1.0f));
                    const float t = fexp2(pj[k] * L);
                    if (k & 1) acc1 += t; else acc0 += t;
                }
                part_lds[hidx][R][lane] += acc0 + acc1;
                xr = xr_next;
            }
        }
        if (J < 7) {
            // ---- x-only tables for phase J+1 (dbuf slot (J+1)&1):
            // Tt: block J+1 self-pairs (diag); Pt: rows J+2 x cols J+1 (panel).
            const float xT = x_lds[((J + 1) << 6) | lane];  // rows & cols blk J+1
#pragma unroll
            for (int k = 0; k < CNT; ++k) {
                const float xjv = bcast_f(xT, start + k);
                const float L   = flog2(fmaxf(xT - xjv, 1.0f));
                Tt[(J + 1) & 1][start + k][lane] = make_float2(-c * L, -a * L);
            }
            if (J < 6) {
                const float xP = x_lds[((J + 2) << 6) | lane];  // rows blk J+2
#pragma unroll
                for (int k = 0; k < CNT; ++k) {
                    const float xjv = bcast_f(xT, start + k);   // cols blk J+1
                    const float L   = flog2(fmaxf(xP - xjv, 1.0f));
                    Pt[(J + 1) & 1][start + k][lane] = make_float2(-c * L, -a * L);
                }
            }
        }
        lds_barrier();  // end of phase J
    }
}

// Wave 0: merge + serial diag + INTEGRATED next-block panel.
// Chain (unchanged from R5, zero cross-lane ops on the recurrence):
//   em_j = A2_j + exp2(fma(sx_j, em_{j-1}, sy_j)),
//   A2_j = readlane(acc_after_{j-2}, j) (1 iter slack), sx/sy extracted 1 early.
// Panel: accN += exp2(fma(Pc.x, em_jl, Pc.y)) per step -- rides in the chain's
// latency shadow; becomes next phase's merge seed. All 64 panel terms valid
// (rows of block J+1 always > cols of block J; fmax handles the d<1 clamp).
// Maskless diag junk: lanes i <= jl add exactly 1.0 per step >= i ->
// subtract (64-lane) at publish; A2_j reads acc_after_{j-2}@j which is clean.
__device__ __forceinline__ void run_diag(const int lane,
                                         float (&expm_lds)[SEQ],
                                         float (&part_lds)[NH][8][64],
                                         float2 (&Tt)[2][64][64],
                                         float2 (&Pt)[2][64][64]) {
    float accN = 0.0f;   // panel seed for block 0 = nothing before it
    for (int J = 0; J < 8; ++J) {
        const int tb = J & 1;
        // ---- merge: my own panel (cols J-1) + helpers' deep (cols 0..J-2)
        float acc = accN;
#pragma unroll
        for (int hh = 0; hh < NH; ++hh) acc += part_lds[hh][J][lane];

        // ---- iter 0 (t_{-1} = 0):
        float2 Tc = Tt[tb][0][lane];
        float em1 = bcast_f(acc, 0);                    // em_0 (uniform)
        float A2  = bcast_f(acc, 1);                    // acc_after_{-1}@1
        float sx  = bcast_f(Tc.x, 1);                   // T[0] @ row 1
        float sy  = bcast_f(Tc.y, 1);
        acc += fexp2(fmaf(Tc.x, em1, Tc.y));            // t_0 -> acc_after_0
        Tc = Tt[tb][1][lane];
        float2 Pc;
        const bool pan = (J < 7);
        if (pan) {
            Pc   = Pt[tb][0][lane];
            accN = fexp2(fmaf(Pc.x, em1, Pc.y));        // panel col 0
            Pc   = Pt[tb][1][lane];
        } else {
            accN = 0.0f;
        }
        // ---- iters 1..63:
#pragma unroll
        for (int jl = 1; jl < 64; ++jl) {
            const float tS = fexp2(fmaf(sx, em1, sy));  // chain: fma+exp2
            em1 = A2 + tS;                              // chain: add -> em_jl
            if (jl < 63) A2 = bcast_f(acc, jl + 1);     // acc_after_{jl-1}, slack
            acc += fexp2(fmaf(Tc.x, em1, Tc.y));        // per-lane diag t_jl
            if (pan) accN += fexp2(fmaf(Pc.x, em1, Pc.y));  // panel col jl
            if (jl < 63) {
                sx = bcast_f(Tc.x, jl + 1);             // T[jl] @ row jl+1
                sy = bcast_f(Tc.y, jl + 1);
                Tc = Tt[tb][jl + 1][lane];              // prefetch col jl+1
                if (pan) Pc = Pt[tb][jl + 1][lane];
            }
        }
        expm_lds[(J << 6) | lane] = acc - (float)(64 - lane);  // publish clean
        lds_barrier();  // end of phase J
    }
}

__global__ void __launch_bounds__(512, 1)
act_r_kernel(const float* __restrict__ sp, const float* __restrict__ w,
             float* __restrict__ out) {
    __shared__ float  x_lds[SEQ];
    __shared__ float  expm_lds[SEQ];
    __shared__ float  part_lds[NH][8][64];   // [helper][row block][lane], deep only
    __shared__ float2 Tt[2][64][64];         // diag  (-cL,-aL), dbuf
    __shared__ float2 Pt[2][64][64];         // panel (-cL,-aL), dbuf
    // LDS total: 2+2+12+64+64 = 144 KiB (<=160 KiB, 1 block/CU as before)

    const int b    = blockIdx.x;
    const int tid  = threadIdx.x;
    const int lane = tid & 63;
    // Wave id as a PROVEN-uniform SGPR value.
    const int uwid = __builtin_amdgcn_readfirstlane(tid >> 6);

    const float a   = w[0];
    const float c   = w[1];
    const float s   = w[2];
    const float tau = w[3];
    const float h   = w[4];
    const float scale = 86400.0f * h;

    for (int k = tid; k < NH * 8 * 64; k += 512) ((float*)part_lds)[k] = 0.0f;
    x_lds[tid] = sp[tid * BATCH + b] * scale;
    lds_barrier();

    // Prologue tables (all 8 waves, 8 cols each): Tt[0] = block-0 self-pairs,
    // Pt[0] = rows block 1 x cols block 0.
    {
        const float xr0 = x_lds[lane];        // rows/cols of block 0
        const float xr1 = x_lds[64 + lane];   // rows of block 1
        const int   s0  = uwid << 3;
#pragma unroll
        for (int k = 0; k < 8; ++k) {
            const float xj = bcast_f(xr0, s0 + k);
            const float L0 = flog2(fmaxf(xr0 - xj, 1.0f));
            Tt[0][s0 + k][lane] = make_float2(-c * L0, -a * L0);
            const float L1 = flog2(fmaxf(xr1 - xj, 1.0f));
            Pt[0][s0 + k][lane] = make_float2(-c * L1, -a * L1);
        }
    }
    lds_barrier();

    if (uwid == 0) {
        // SIMD0 is wave0-exclusive (wave4 parked): trans pipe belongs to the
        // chain + integrated panel (3 exp2/step = 24 cy, ~= chain latency).
        __builtin_amdgcn_s_setprio(2);
        run_diag(lane, expm_lds, part_lds, Tt, Pt);
        __builtin_amdgcn_s_setprio(0);
    } else if (uwid == 4) {
        // Parked: match the one-barrier-per-phase sequence.
        for (int J = 0; J < 8; ++J) lds_barrier();
    } else {
        // 6 helpers cover 64 cols: w1:0(11) w2:11(11) w3:22(11) w5:33(11)
        //                          w6:44(10) w7:54(10)
        if (uwid < 4) {
            run_helper<11>((uwid - 1) * 11, uwid - 1, lane, a, c,
                           x_lds, expm_lds, part_lds, Tt, Pt);
        } else if (uwid == 5) {
            run_helper<11>(33, 3, lane, a, c, x_lds, expm_lds, part_lds, Tt, Pt);
        } else {
            run_helper<10>(44 + (uwid - 6) * 10, uwid - 2, lane, a, c,
                           x_lds, expm_lds, part_lds, Tt, Pt);
        }
    }

    // ---- epilogue: all 512 threads, one output each (i = tid, skip 0)
    if (tid >= 1) {
        const float inv_ln2 = 1.4426950408889634f;
        const float q = tau / s * inv_ln2 - flog2(expm_lds[tid]) / s;
        out[(tid - 1) * BATCH + b] = 1.0f / (1.0f + fexp2(q));
    }
}

extern "C" void kernel_launch(void* const* d_in, const int* in_sizes, int n_in,
                              void* d_out, int out_size, void* d_ws, size_t ws_size,
                              hipStream_t stream) {
    const float* sp = (const float*)d_in[0];  // [512, 256, 1] f32
    const float* w  = (const float*)d_in[1];  // [5] f32
    float* out = (float*)d_out;               // [511, 256, 1] f32
    (void)in_sizes; (void)n_in; (void)out_size; (void)d_ws; (void)ws_size;

    act_r_kernel<<<dim3(BATCH), dim3(512), 0, stream>>>(sp, w, out);
}